// Round 11
// baseline (241.330 us; speedup 1.0000x reference)
//
#include <hip/hip_runtime.h>

// P=1,048,576 params; E=8,388,608 edges; T=4,194,304 bytes; N=2,097,152 tokens.
//
// Measured HW facts driving this design:
//  - global atomicAdd caps at ~20.4 G/s (R1-R3) -> all accumulation in LDS.
//  - scattered small stores RMW-amplify ~3x (R4) -> staged counting-sort
//    writes as runs; >=128B required (R15), 256B better (R21: A FETCH
//    excess halved, A ~78 -> ~72, total 242.8 -> 238.2).
//  - NT loads on read-once streams keep fp L2-resident (R10); intermediates
//    written with normal cached stores (R11) -> L3-resident for next phase.
//  - R12: pidx in record -> phaseA gather-free. R13/R15: MLP batching must
//    keep wave-coalesced stride. R16: NB2=256 + barrier fold. R17: x4
//    strip-mine both C passes.
//  - R18 REGRESSION: fp gather in A costs +16us (no slack at 2 blk/CU).
//  - R19/R20 REGRESSIONS: cooperative grid.sync AND device-side ticket-spin
//    barriers both lose badly to plain kernel-launch boundaries (~10-15us).
//    Phase boundaries are irreducible at this level; stop attacking them.
//  - R22 (this round): phaseC pass1 strip-mine x4 -> x8 (16 independent
//    gathers in flight; VGPR ~50 < 64 keeps 2 blk/CU); pass2 replaces the
//    float divide with LDS rtab[c]=1/(4c) (wfx = rint(s/(4c)), error <=
//    1 ulp of 2^-19 -- negligible vs 5e-4 absmax); phaseD x8 batching.
//    If C stays ~81: C is issue-bound at its plateau -> declare ceiling.
//
// rec64 = pos_low(13) | tok(21)<<13 | pidx(21)<<34 | bucket(9)<<55.
// acc u32 = cnt*2^26 + sum(fx), fx = round(fp[pidx] * 2^21)  (cnt<=~25).
// rec2 = tok_low(13) | wfx<<13,  wfx = round(w * 2^19) (19-bit signed).

typedef unsigned long long u64;
typedef unsigned int uint;
typedef int  vi4  __attribute__((ext_vector_type(4)));
typedef unsigned long long uv2 __attribute__((ext_vector_type(2)));

constexpr int NB   = 512;        // byte buckets  (bpos >> 13)
constexpr int PPB  = 8192;       // positions per byte bucket
constexpr int NB2  = 256;        // token buckets (tok >> 13)
constexpr int TOKB = 8192;       // tokens per token bucket
constexpr int CAP  = 17408;      // per-bucket capacity (mean 16384 + 8 sigma)
constexpr int CAP2 = 34816;      // per-token-bucket capacity (mean 32768 + 11s)

constexpr float V_SCALE = 2097152.0f;        // 2^21
constexpr float W_INV   = 1.0f / 524288.0f;  // 2^-19

// Exclusive scan of 512 LDS entries by wave 0 only. lbase[512] = total.
__device__ __forceinline__ void wave_scan512(const uint* hist, uint* lbase,
                                             int t) {
    if (t < 64) {
        uint h[8];
        uint run = 0;
        #pragma unroll
        for (int j = 0; j < 8; ++j) { h[j] = run; run += hist[t * 8 + j]; }
        uint tot = run, inc = tot;
        #pragma unroll
        for (int d = 1; d < 64; d <<= 1) {
            uint up = __shfl_up(inc, d, 64);
            if (t >= d) inc += up;
        }
        uint excl = inc - tot;
        #pragma unroll
        for (int j = 0; j < 8; ++j) lbase[t * 8 + j] = excl + h[j];
        if (t == 63) lbase[512] = inc;
    }
}

// Exclusive scan of 256 LDS entries by wave 0 only. lbase[256] = total.
__device__ __forceinline__ void wave_scan256(const uint* hist, uint* lbase,
                                             int t) {
    if (t < 64) {
        uint h[4];
        uint run = 0;
        #pragma unroll
        for (int j = 0; j < 4; ++j) { h[j] = run; run += hist[t * 4 + j]; }
        uint tot = run, inc = tot;
        #pragma unroll
        for (int d = 1; d < 64; d <<= 1) {
            uint up = __shfl_up(inc, d, 64);
            if (t >= d) inc += up;
        }
        uint excl = inc - tot;
        #pragma unroll
        for (int j = 0; j < 4; ++j) lbase[t * 4 + j] = excl + h[j];
        if (t == 63) lbase[256] = inc;
    }
}

// ---------------- Phase A: bin edges into 512 byte-buckets ----------------
// Gather-free streaming sort. R21: both chunks histogrammed up front, ONE
// combined gcur allocation per bucket -> adjacent 256B runs.
constexpr int A_THREADS = 1024;
constexpr int A_EPT     = 8;
constexpr int A_CHUNK   = A_THREADS * A_EPT;   // 8192
constexpr int A_CPB     = 2;                   // chunks per block

__global__ __launch_bounds__(A_THREADS, 8) void phaseA(
    const int* __restrict__ pidx, const int* __restrict__ bpos,
    const int* __restrict__ tidx, u64* __restrict__ recs,
    uint* __restrict__ gcur, int E)
{
    __shared__ u64 stage[A_CHUNK];                 // 64 KB
    __shared__ uint hist0[NB], hist1[NB], lcur[NB], gbase[NB], lbase[NB + 1];
    int t = threadIdx.x;

    int c0 = blockIdx.x * A_CPB;
    int be0 = c0 * A_CHUNK + t * A_EPT;
    int be1 = (c0 + 1) * A_CHUNK + t * A_EPT;
    bool v0 = (be0 + A_EPT) <= E;
    bool v1 = (be1 + A_EPT) <= E;

    // chunk0: all three streams; chunk1: bpos only (for the histogram)
    vi4 ab0, ab1, ap0, ap1, ak0, ak1, cb0, cb1;
    if (v0) {
        ab0 = __builtin_nontemporal_load((const vi4*)(bpos + be0));
        ab1 = __builtin_nontemporal_load((const vi4*)(bpos + be0 + 4));
        ap0 = __builtin_nontemporal_load((const vi4*)(pidx + be0));
        ap1 = __builtin_nontemporal_load((const vi4*)(pidx + be0 + 4));
        ak0 = __builtin_nontemporal_load((const vi4*)(tidx + be0));
        ak1 = __builtin_nontemporal_load((const vi4*)(tidx + be0 + 4));
    }
    if (v1) {
        cb0 = __builtin_nontemporal_load((const vi4*)(bpos + be1));
        cb1 = __builtin_nontemporal_load((const vi4*)(bpos + be1 + 4));
    }

    if (t < NB) { hist0[t] = 0u; hist1[t] = 0u; lcur[t] = 0u; }
    __syncthreads();

    // histogram both chunks
    if (v0) {
        atomicAdd(&hist0[((uint)ab0.x) >> 13], 1u);
        atomicAdd(&hist0[((uint)ab0.y) >> 13], 1u);
        atomicAdd(&hist0[((uint)ab0.z) >> 13], 1u);
        atomicAdd(&hist0[((uint)ab0.w) >> 13], 1u);
        atomicAdd(&hist0[((uint)ab1.x) >> 13], 1u);
        atomicAdd(&hist0[((uint)ab1.y) >> 13], 1u);
        atomicAdd(&hist0[((uint)ab1.z) >> 13], 1u);
        atomicAdd(&hist0[((uint)ab1.w) >> 13], 1u);
    } else {
        for (int j = 0; j < A_EPT; ++j) {
            int e = be0 + j;
            if (e < E) atomicAdd(&hist0[((uint)bpos[e]) >> 13], 1u);
        }
    }
    if (v1) {
        atomicAdd(&hist1[((uint)cb0.x) >> 13], 1u);
        atomicAdd(&hist1[((uint)cb0.y) >> 13], 1u);
        atomicAdd(&hist1[((uint)cb0.z) >> 13], 1u);
        atomicAdd(&hist1[((uint)cb0.w) >> 13], 1u);
        atomicAdd(&hist1[((uint)cb1.x) >> 13], 1u);
        atomicAdd(&hist1[((uint)cb1.y) >> 13], 1u);
        atomicAdd(&hist1[((uint)cb1.z) >> 13], 1u);
        atomicAdd(&hist1[((uint)cb1.w) >> 13], 1u);
    } else {
        for (int j = 0; j < A_EPT; ++j) {
            int e = be1 + j;
            if (e < E) atomicAdd(&hist1[((uint)bpos[e]) >> 13], 1u);
        }
    }
    __syncthreads();

    // wave 0 scans chunk0; waves 8-15 do ONE combined allocation per bucket.
    wave_scan512(hist0, lbase, t);
    if (t >= 512) {
        int b = t - 512;
        gbase[b] = atomicAdd(&gcur[b], hist0[b] + hist1[b]);
    }
    __syncthreads();

    auto emit = [&](int p, int tk, int pi) {
        uint b = ((uint)p) >> 13;
        u64 rec = (u64)(uint)(p & (PPB - 1))
                | ((u64)(uint)tk << 13)
                | ((u64)(uint)pi << 34)
                | ((u64)b << 55);
        uint off = lbase[b] + atomicAdd(&lcur[b], 1u);
        stage[off] = rec;
    };

    // emit chunk0
    if (v0) {
        emit(ab0.x, ak0.x, ap0.x); emit(ab0.y, ak0.y, ap0.y);
        emit(ab0.z, ak0.z, ap0.z); emit(ab0.w, ak0.w, ap0.w);
        emit(ab1.x, ak1.x, ap1.x); emit(ab1.y, ak1.y, ap1.y);
        emit(ab1.z, ak1.z, ap1.z); emit(ab1.w, ak1.w, ap1.w);
    } else {
        for (int j = 0; j < A_EPT; ++j) {
            int e = be0 + j;
            if (e < E) emit(bpos[e], tidx[e], pidx[e]);
        }
    }

    // prefetch chunk1 pidx/tidx now; latency drains under write-out below.
    vi4 cp0, cp1, ck0, ck1;
    if (v1) {
        cp0 = __builtin_nontemporal_load((const vi4*)(pidx + be1));
        cp1 = __builtin_nontemporal_load((const vi4*)(pidx + be1 + 4));
        ck0 = __builtin_nontemporal_load((const vi4*)(tidx + be1));
        ck1 = __builtin_nontemporal_load((const vi4*)(tidx + be1 + 4));
    }
    __syncthreads();

    // write-out chunk0 at gbase (cached stores -> L2 write-combine)
    uint total0 = lbase[NB];
    for (uint i = t; i < total0; i += A_THREADS) {
        u64 rc = stage[i];
        int b = (int)(rc >> 55);
        uint dst = gbase[b] + (i - lbase[b]);
        if (dst < (uint)CAP)
            recs[(size_t)b * CAP + dst] = rc;
    }
    __syncthreads();

    // rescan for chunk1; reset lcur
    if (t < NB) lcur[t] = 0u;
    wave_scan512(hist1, lbase, t);
    __syncthreads();

    // emit chunk1
    if (v1) {
        emit(cb0.x, ck0.x, cp0.x); emit(cb0.y, ck0.y, cp0.y);
        emit(cb0.z, ck0.z, cp0.z); emit(cb0.w, ck0.w, cp0.w);
        emit(cb1.x, ck1.x, cp1.x); emit(cb1.y, ck1.y, cp1.y);
        emit(cb1.z, ck1.z, cp1.z); emit(cb1.w, ck1.w, cp1.w);
    } else {
        for (int j = 0; j < A_EPT; ++j) {
            int e = be1 + j;
            if (e < E) emit(bpos[e], tidx[e], pidx[e]);
        }
    }
    __syncthreads();

    // write-out chunk1 immediately after chunk0's run (256B contiguous)
    uint total1 = lbase[NB];
    for (uint i = t; i < total1; i += A_THREADS) {
        u64 rc = stage[i];
        int b = (int)(rc >> 55);
        uint dst = gbase[b] + hist0[b] + (i - lbase[b]);
        if (dst < (uint)CAP)
            recs[(size_t)b * CAP + dst] = rc;
    }
}

// ------- Phase C: per byte-bucket accumulate + emit token-bucket recs -------
constexpr int C_THREADS = 1024;
constexpr int C_CHUNK   = 8192;
constexpr int C_MAXCH   = (CAP + C_CHUNK - 1) / C_CHUNK;   // 3

__global__ __launch_bounds__(C_THREADS, 8) void phaseC(
    const float* __restrict__ fp,
    const u64* __restrict__ recs, const uint* __restrict__ gcur,
    uint* __restrict__ rec2, uint* __restrict__ gcur2)
{
    __shared__ uint acc[PPB];               // 32 KB
    __shared__ uint stage2[C_CHUNK];        // 32 KB
    __shared__ uint histc[C_MAXCH][NB2];    // 3 KB
    __shared__ uint lcur[NB2], gb[NB2], lbase[NB2 + 1];   // ~3 KB
    __shared__ float rtab[64];              // 1/(4c) table, c<=~25
    int t = threadIdx.x;
    int b = blockIdx.x;
    for (int i = t; i < PPB; i += C_THREADS) acc[i] = 0u;
    for (int i = t; i < C_MAXCH * NB2; i += C_THREADS) (&histc[0][0])[i] = 0u;
    if (t < NB2) lcur[t] = 0u;
    if (t < 64) rtab[t] = (t > 0) ? (1.0f / (4.0f * (float)t)) : 0.0f;
    __syncthreads();

    uint n = min(gcur[b], (uint)CAP);
    const u64* r = recs + (size_t)b * CAP;

    // pass 1: strip-mined x8 with COALESCED stride (each NT load = 1KB/wave).
    // 8 independent rec loads -> 16 independent fp gathers -> 32 LDS atomics.
    auto upd = [&](u64 rc, float v, uint ch) {
        int fx = (int)rintf(v * V_SCALE);
        atomicAdd(&acc[(uint)rc & (PPB - 1)], (uint)((1 << 26) + fx));
        atomicAdd(&histc[ch][(uint)(rc >> 26) & 0xFFu], 1u);  // tok>>13
    };
    uint np = n >> 1;                        // uv2 pairs
    const uv2* pr = (const uv2*)r;
    uint i = t;
    for (; i + 7u * C_THREADS < np; i += 8u * C_THREADS) {
        uv2 x0 = __builtin_nontemporal_load(pr + i);
        uv2 x1 = __builtin_nontemporal_load(pr + i + C_THREADS);
        uv2 x2 = __builtin_nontemporal_load(pr + i + 2u * C_THREADS);
        uv2 x3 = __builtin_nontemporal_load(pr + i + 3u * C_THREADS);
        uv2 x4 = __builtin_nontemporal_load(pr + i + 4u * C_THREADS);
        uv2 x5 = __builtin_nontemporal_load(pr + i + 5u * C_THREADS);
        uv2 x6 = __builtin_nontemporal_load(pr + i + 6u * C_THREADS);
        uv2 x7 = __builtin_nontemporal_load(pr + i + 7u * C_THREADS);
        float v0 = fp[(uint)(x0.x >> 34) & 0x1FFFFFu];
        float v1 = fp[(uint)(x0.y >> 34) & 0x1FFFFFu];
        float v2 = fp[(uint)(x1.x >> 34) & 0x1FFFFFu];
        float v3 = fp[(uint)(x1.y >> 34) & 0x1FFFFFu];
        float v4 = fp[(uint)(x2.x >> 34) & 0x1FFFFFu];
        float v5 = fp[(uint)(x2.y >> 34) & 0x1FFFFFu];
        float v6 = fp[(uint)(x3.x >> 34) & 0x1FFFFFu];
        float v7 = fp[(uint)(x3.y >> 34) & 0x1FFFFFu];
        float v8 = fp[(uint)(x4.x >> 34) & 0x1FFFFFu];
        float v9 = fp[(uint)(x4.y >> 34) & 0x1FFFFFu];
        float va = fp[(uint)(x5.x >> 34) & 0x1FFFFFu];
        float vb = fp[(uint)(x5.y >> 34) & 0x1FFFFFu];
        float vc = fp[(uint)(x6.x >> 34) & 0x1FFFFFu];
        float vd = fp[(uint)(x6.y >> 34) & 0x1FFFFFu];
        float ve = fp[(uint)(x7.x >> 34) & 0x1FFFFFu];
        float vf = fp[(uint)(x7.y >> 34) & 0x1FFFFFu];
        uint c0 = i >> 12;                         // pair>>12 == elem>>13
        uint c1 = (i + C_THREADS) >> 12;
        uint c2 = (i + 2u * C_THREADS) >> 12;
        uint c3 = (i + 3u * C_THREADS) >> 12;
        uint c4 = (i + 4u * C_THREADS) >> 12;
        uint c5 = (i + 5u * C_THREADS) >> 12;
        uint c6 = (i + 6u * C_THREADS) >> 12;
        uint c7 = (i + 7u * C_THREADS) >> 12;
        upd(x0.x, v0, c0); upd(x0.y, v1, c0);
        upd(x1.x, v2, c1); upd(x1.y, v3, c1);
        upd(x2.x, v4, c2); upd(x2.y, v5, c2);
        upd(x3.x, v6, c3); upd(x3.y, v7, c3);
        upd(x4.x, v8, c4); upd(x4.y, v9, c4);
        upd(x5.x, va, c5); upd(x5.y, vb, c5);
        upd(x6.x, vc, c6); upd(x6.y, vd, c6);
        upd(x7.x, ve, c7); upd(x7.y, vf, c7);
    }
    for (; i + 3u * C_THREADS < np; i += 4u * C_THREADS) {
        uv2 x0 = __builtin_nontemporal_load(pr + i);
        uv2 x1 = __builtin_nontemporal_load(pr + i + C_THREADS);
        uv2 x2 = __builtin_nontemporal_load(pr + i + 2u * C_THREADS);
        uv2 x3 = __builtin_nontemporal_load(pr + i + 3u * C_THREADS);
        float v0 = fp[(uint)(x0.x >> 34) & 0x1FFFFFu];
        float v1 = fp[(uint)(x0.y >> 34) & 0x1FFFFFu];
        float v2 = fp[(uint)(x1.x >> 34) & 0x1FFFFFu];
        float v3 = fp[(uint)(x1.y >> 34) & 0x1FFFFFu];
        float v4 = fp[(uint)(x2.x >> 34) & 0x1FFFFFu];
        float v5 = fp[(uint)(x2.y >> 34) & 0x1FFFFFu];
        float v6 = fp[(uint)(x3.x >> 34) & 0x1FFFFFu];
        float v7 = fp[(uint)(x3.y >> 34) & 0x1FFFFFu];
        uint c0 = i >> 12;
        uint c1 = (i + C_THREADS) >> 12;
        uint c2 = (i + 2u * C_THREADS) >> 12;
        uint c3 = (i + 3u * C_THREADS) >> 12;
        upd(x0.x, v0, c0); upd(x0.y, v1, c0);
        upd(x1.x, v2, c1); upd(x1.y, v3, c1);
        upd(x2.x, v4, c2); upd(x2.y, v5, c2);
        upd(x3.x, v6, c3); upd(x3.y, v7, c3);
    }
    for (; i < np; i += C_THREADS) {
        uv2 x = __builtin_nontemporal_load(pr + i);
        uint ch = i >> 12;
        float va = fp[(uint)(x.x >> 34) & 0x1FFFFFu];
        float vb = fp[(uint)(x.y >> 34) & 0x1FFFFFu];
        upd(x.x, va, ch); upd(x.y, vb, ch);
    }
    if ((n & 1u) && t == 0) {
        u64 rc = __builtin_nontemporal_load(r + n - 1);
        upd(rc, fp[(uint)(rc >> 34) & 0x1FFFFFu], (n - 1) / C_CHUNK);
    }
    __syncthreads();

    // ONE global-cursor atomic per bucket per block (wave 8), overlapped
    // with wave 0's chunk-0 scan below.
    if (t >= 512 && t < 512 + NB2) {
        int tb = t - 512;
        uint tot = histc[0][tb];
        #pragma unroll
        for (int c = 1; c < C_MAXCH; ++c) tot += histc[c][tb];
        gb[tb] = atomicAdd(&gcur2[tb], tot);
    }

    // pass 2: strip-mined x4 chunked decode + LDS-staged emit + write-out.
    // wfx = rint(s * 2^-21 / c * 2^19) = rint(s * (1/(4c))) via rtab (no
    // divide). gb/lcur update folded into write-out -> 3 barriers/chunk.
    auto emit = [&](u64 rc, uint a) {
        uint tok = (uint)(rc >> 13) & 0x1FFFFFu;
        uint c = (a + (1u << 25)) >> 26;        // exact count >= 1
        int s = (int)(a - (c << 26));           // signed sum * 2^21
        int wfx = (int)rintf((float)s * rtab[c & 63u]);
        uint tb = tok >> 13;
        uint off = lbase[tb] + atomicAdd(&lcur[tb], 1u);
        stage2[off] = (tok & (TOKB - 1)) | ((uint)wfx << 13);
    };
    uint ch = 0;
    for (uint c0 = 0; c0 < n; c0 += C_CHUNK, ++ch) {
        uint m = min((uint)C_CHUNK, n - c0);
        wave_scan256(histc[ch], lbase, t);
        __syncthreads();

        uint mp = m >> 1;
        const uv2* pc = (const uv2*)(r + c0);
        uint j = t;
        for (; j + 3u * C_THREADS < mp; j += 4u * C_THREADS) {
            uv2 x0 = __builtin_nontemporal_load(pc + j);
            uv2 x1 = __builtin_nontemporal_load(pc + j + C_THREADS);
            uv2 x2 = __builtin_nontemporal_load(pc + j + 2u * C_THREADS);
            uv2 x3 = __builtin_nontemporal_load(pc + j + 3u * C_THREADS);
            uint a0 = acc[(uint)x0.x & (PPB - 1)];
            uint a1 = acc[(uint)x0.y & (PPB - 1)];
            uint a2 = acc[(uint)x1.x & (PPB - 1)];
            uint a3 = acc[(uint)x1.y & (PPB - 1)];
            uint a4 = acc[(uint)x2.x & (PPB - 1)];
            uint a5 = acc[(uint)x2.y & (PPB - 1)];
            uint a6 = acc[(uint)x3.x & (PPB - 1)];
            uint a7 = acc[(uint)x3.y & (PPB - 1)];
            emit(x0.x, a0); emit(x0.y, a1);
            emit(x1.x, a2); emit(x1.y, a3);
            emit(x2.x, a4); emit(x2.y, a5);
            emit(x3.x, a6); emit(x3.y, a7);
        }
        for (; j < mp; j += C_THREADS) {
            uv2 x = __builtin_nontemporal_load(pc + j);
            uint a0 = acc[(uint)x.x & (PPB - 1)];
            uint a1 = acc[(uint)x.y & (PPB - 1)];
            emit(x.x, a0); emit(x.y, a1);
        }
        if ((m & 1u) && t == 0) {
            u64 rc = __builtin_nontemporal_load(r + c0 + m - 1);
            emit(rc, acc[(uint)rc & (PPB - 1)]);
        }
        __syncthreads();
        // write-out: wave w copies buckets w, w+16, ... as contiguous runs
        // (normal cached stores -> rec2 stays L3-resident for phaseD).
        // lane 0 of the owning wave advances gb and resets lcur in-place.
        int w = t >> 6, lane = t & 63;
        for (int tb = w; tb < NB2; tb += 16) {
            uint base = lbase[tb];
            uint len  = lbase[tb + 1] - base;
            uint g    = gb[tb];
            for (uint q = lane; q < len; q += 64) {
                uint dst = g + q;
                if (dst < (uint)CAP2)
                    rec2[(size_t)tb * CAP2 + dst] = stage2[base + q];
            }
            if (lane == 0) { gb[tb] = g + len; lcur[tb] = 0u; }
        }
        __syncthreads();
    }
}

// ---------------- Phase D: per token-bucket reduce + output ----------------
constexpr int D_THREADS = 1024;

__global__ __launch_bounds__(D_THREADS) void phaseD(
    const uint* __restrict__ rec2, const uint* __restrict__ gcur2,
    float* __restrict__ out, int N)
{
    __shared__ int facc[TOKB];   // 32 KB
    int t = threadIdx.x;
    int b = blockIdx.x;
    for (int i = t; i < TOKB; i += D_THREADS) facc[i] = 0;
    __syncthreads();
    uint n = min(gcur2[b], (uint)CAP2);
    const uint* r = rec2 + (size_t)b * CAP2;
    uint n4 = n >> 2;
    uint i = t;
    // 8-deep coalesced load batching, then 32 fire-and-forget LDS atomics.
    for (; i + 7u * D_THREADS < n4; i += 8u * D_THREADS) {
        uint4 q[8];
        #pragma unroll
        for (int k = 0; k < 8; ++k)
            q[k] = ((const uint4*)r)[i + (uint)k * D_THREADS];
        #pragma unroll
        for (int k = 0; k < 8; ++k) {
            atomicAdd(&facc[q[k].x & (TOKB - 1)], ((int)q[k].x) >> 13);
            atomicAdd(&facc[q[k].y & (TOKB - 1)], ((int)q[k].y) >> 13);
            atomicAdd(&facc[q[k].z & (TOKB - 1)], ((int)q[k].z) >> 13);
            atomicAdd(&facc[q[k].w & (TOKB - 1)], ((int)q[k].w) >> 13);
        }
    }
    for (; i < n4; i += D_THREADS) {
        uint4 q = ((const uint4*)r)[i];
        atomicAdd(&facc[q.x & (TOKB - 1)], ((int)q.x) >> 13);
        atomicAdd(&facc[q.y & (TOKB - 1)], ((int)q.y) >> 13);
        atomicAdd(&facc[q.z & (TOKB - 1)], ((int)q.z) >> 13);
        atomicAdd(&facc[q.w & (TOKB - 1)], ((int)q.w) >> 13);
    }
    for (uint k = (n4 << 2) + t; k < n; k += D_THREADS) {
        uint rc = r[k];
        atomicAdd(&facc[rc & (TOKB - 1)], ((int)rc) >> 13);
    }
    __syncthreads();
    int base = b * TOKB;
    for (int i2 = t; i2 < TOKB; i2 += D_THREADS) {
        int idx = base + i2;
        if (idx < N)
            __builtin_nontemporal_store((float)facc[i2] * W_INV, &out[idx]);
    }
}

// ---------------- fallback (R2 path) if workspace too small ----------------
__global__ void fb_scatter(const float* __restrict__ fp,
                           const int* __restrict__ pidx,
                           const int* __restrict__ bpos,
                           u64* __restrict__ bacc, int E) {
    int e = blockIdx.x * blockDim.x + threadIdx.x;
    if (e < E) {
        float v = fp[pidx[e]];
        long long fx = (long long)rintf(v * 4294967296.0f);
        atomicAdd(&bacc[bpos[e]], (1ULL << 39) + (u64)fx);
    }
}

__global__ void fb_tokens(const u64* __restrict__ bacc,
                          const int* __restrict__ bpos,
                          const int* __restrict__ tidx,
                          float* __restrict__ out, int E) {
    int e = blockIdx.x * blockDim.x + threadIdx.x;
    if (e < E) {
        u64 v = bacc[bpos[e]];
        long long cnt = (long long)((v + (1ULL << 38)) >> 39);
        long long s   = (long long)(v - ((u64)cnt << 39));
        atomicAdd(&out[tidx[e]], (float)s * (1.0f / 4294967296.0f) / (float)cnt);
    }
}

extern "C" void kernel_launch(void* const* d_in, const int* in_sizes, int n_in,
                              void* d_out, int out_size, void* d_ws, size_t ws_size,
                              hipStream_t stream) {
    const float* flat_params   = (const float*)d_in[0];
    const int*   occ_param_idx = (const int*)d_in[1];
    const int*   occ_byte_pos  = (const int*)d_in[2];
    const int*   occ_token_idx = (const int*)d_in[3];

    const int E = in_sizes[1];            // 8,388,608
    const int N = out_size;               // 2,097,152

    const size_t REC_BYTES  = (size_t)NB  * CAP  * 8;   // 71.3 MB
    const size_t REC2_BYTES = (size_t)NB2 * CAP2 * 4;   // 35.7 MB
    const size_t NEED = 4096 + REC_BYTES + REC2_BYTES;  // ~107 MB

    if (ws_size >= NEED && N <= NB2 * TOKB) {
        uint* gcur  = (uint*)d_ws;                  // 2 KB (512 u32)
        uint* gcur2 = (uint*)((char*)d_ws + 2048);  // 1 KB (256 u32)
        u64* recs = (u64*)((char*)d_ws + 4096);
        uint* rec2 = (uint*)((char*)d_ws + 4096 + REC_BYTES);

        (void)hipMemsetAsync(d_ws, 0, 4096, stream);   // both cursor arrays

        int nchunks = (E + A_CHUNK - 1) / A_CHUNK;          // 1024
        int gridA = (nchunks + A_CPB - 1) / A_CPB;          // 512
        phaseA<<<gridA, A_THREADS, 0, stream>>>(occ_param_idx, occ_byte_pos,
                                                occ_token_idx, recs, gcur, E);
        phaseC<<<NB, C_THREADS, 0, stream>>>(flat_params, recs, gcur,
                                             rec2, gcur2);
        phaseD<<<NB2, D_THREADS, 0, stream>>>(rec2, gcur2, (float*)d_out, N);
    } else {
        u64* bacc = (u64*)d_ws;
        (void)hipMemsetAsync(bacc, 0, (size_t)4194304 * 8, stream);
        (void)hipMemsetAsync(d_out, 0, (size_t)N * sizeof(float), stream);
        int gridE = (E + 255) / 256;
        fb_scatter<<<gridE, 256, 0, stream>>>(flat_params, occ_param_idx,
                                              occ_byte_pos, bacc, E);
        fb_tokens<<<gridE, 256, 0, stream>>>(bacc, occ_byte_pos,
                                             occ_token_idx, (float*)d_out, E);
    }
}

// Round 12
// 237.559 us; speedup vs baseline: 1.0159x; 1.0159x over previous
//
#include <hip/hip_runtime.h>

// P=1,048,576 params; E=8,388,608 edges; T=4,194,304 bytes; N=2,097,152 tokens.
//
// Measured HW facts driving this design:
//  - global atomicAdd caps at ~20.4 G/s (R1-R3) -> all accumulation in LDS.
//  - scattered small stores RMW-amplify ~3x (R4) -> staged counting-sort
//    writes as runs; >=128B required (R15), 256B better (R21: A FETCH
//    excess halved, A ~78 -> ~72, total 242.8 -> 238.2).
//  - NT loads on read-once streams keep fp L2-resident (R10); intermediates
//    written with normal cached stores (R11) -> L3-resident for next phase.
//  - R12: pidx in record -> phaseA gather-free. R13/R15: MLP batching must
//    keep wave-coalesced stride. R16: NB2=256 + barrier fold. R17: x4
//    strip-mine both C passes.
//  - R18 REGRESSION: fp gather in A costs +16us (no slack at 2 blk/CU).
//  - R19/R20 REGRESSIONS: cooperative grid.sync AND device-side ticket-spin
//    barriers both lose badly to plain kernel-launch boundaries (~10-15us).
//    Phase boundaries are irreducible at this level.
//  - R22 NULL (reverted): pass1 x8 strip-mine, pass2 rtab divide-free,
//    phaseD x8 -- C flat at 80.4 (VGPR stayed 32, VALUBusy fell), total
//    241.3 > 238.2. CONCLUSION: phaseC is at its LDS-atomic/issue-bound
//    plateau (~80us across 5 structural variants); phaseD unresponsive to
//    all restructures. This kernel = exact R21 best (238.2us).
//
// rec64 = pos_low(13) | tok(21)<<13 | pidx(21)<<34 | bucket(9)<<55.
// acc u32 = cnt*2^26 + sum(fx), fx = round(fp[pidx] * 2^21)  (cnt<=~25).
// rec2 = tok_low(13) | wfx<<13,  wfx = round(w * 2^19) (19-bit signed).

typedef unsigned long long u64;
typedef unsigned int uint;
typedef int  vi4  __attribute__((ext_vector_type(4)));
typedef unsigned long long uv2 __attribute__((ext_vector_type(2)));

constexpr int NB   = 512;        // byte buckets  (bpos >> 13)
constexpr int PPB  = 8192;       // positions per byte bucket
constexpr int NB2  = 256;        // token buckets (tok >> 13)
constexpr int TOKB = 8192;       // tokens per token bucket
constexpr int CAP  = 17408;      // per-bucket capacity (mean 16384 + 8 sigma)
constexpr int CAP2 = 34816;      // per-token-bucket capacity (mean 32768 + 11s)

constexpr float V_SCALE = 2097152.0f;        // 2^21
constexpr float V_INV   = 1.0f / 2097152.0f;
constexpr float W_SCALE = 524288.0f;         // 2^19
constexpr float W_INV   = 1.0f / 524288.0f;

// Exclusive scan of 512 LDS entries by wave 0 only. lbase[512] = total.
__device__ __forceinline__ void wave_scan512(const uint* hist, uint* lbase,
                                             int t) {
    if (t < 64) {
        uint h[8];
        uint run = 0;
        #pragma unroll
        for (int j = 0; j < 8; ++j) { h[j] = run; run += hist[t * 8 + j]; }
        uint tot = run, inc = tot;
        #pragma unroll
        for (int d = 1; d < 64; d <<= 1) {
            uint up = __shfl_up(inc, d, 64);
            if (t >= d) inc += up;
        }
        uint excl = inc - tot;
        #pragma unroll
        for (int j = 0; j < 8; ++j) lbase[t * 8 + j] = excl + h[j];
        if (t == 63) lbase[512] = inc;
    }
}

// Exclusive scan of 256 LDS entries by wave 0 only. lbase[256] = total.
__device__ __forceinline__ void wave_scan256(const uint* hist, uint* lbase,
                                             int t) {
    if (t < 64) {
        uint h[4];
        uint run = 0;
        #pragma unroll
        for (int j = 0; j < 4; ++j) { h[j] = run; run += hist[t * 4 + j]; }
        uint tot = run, inc = tot;
        #pragma unroll
        for (int d = 1; d < 64; d <<= 1) {
            uint up = __shfl_up(inc, d, 64);
            if (t >= d) inc += up;
        }
        uint excl = inc - tot;
        #pragma unroll
        for (int j = 0; j < 4; ++j) lbase[t * 4 + j] = excl + h[j];
        if (t == 63) lbase[256] = inc;
    }
}

// ---------------- Phase A: bin edges into 512 byte-buckets ----------------
// Gather-free streaming sort. R21: both chunks histogrammed up front, ONE
// combined gcur allocation per bucket -> adjacent 256B runs.
constexpr int A_THREADS = 1024;
constexpr int A_EPT     = 8;
constexpr int A_CHUNK   = A_THREADS * A_EPT;   // 8192
constexpr int A_CPB     = 2;                   // chunks per block

__global__ __launch_bounds__(A_THREADS, 8) void phaseA(
    const int* __restrict__ pidx, const int* __restrict__ bpos,
    const int* __restrict__ tidx, u64* __restrict__ recs,
    uint* __restrict__ gcur, int E)
{
    __shared__ u64 stage[A_CHUNK];                 // 64 KB
    __shared__ uint hist0[NB], hist1[NB], lcur[NB], gbase[NB], lbase[NB + 1];
    int t = threadIdx.x;

    int c0 = blockIdx.x * A_CPB;
    int be0 = c0 * A_CHUNK + t * A_EPT;
    int be1 = (c0 + 1) * A_CHUNK + t * A_EPT;
    bool v0 = (be0 + A_EPT) <= E;
    bool v1 = (be1 + A_EPT) <= E;

    // chunk0: all three streams; chunk1: bpos only (for the histogram)
    vi4 ab0, ab1, ap0, ap1, ak0, ak1, cb0, cb1;
    if (v0) {
        ab0 = __builtin_nontemporal_load((const vi4*)(bpos + be0));
        ab1 = __builtin_nontemporal_load((const vi4*)(bpos + be0 + 4));
        ap0 = __builtin_nontemporal_load((const vi4*)(pidx + be0));
        ap1 = __builtin_nontemporal_load((const vi4*)(pidx + be0 + 4));
        ak0 = __builtin_nontemporal_load((const vi4*)(tidx + be0));
        ak1 = __builtin_nontemporal_load((const vi4*)(tidx + be0 + 4));
    }
    if (v1) {
        cb0 = __builtin_nontemporal_load((const vi4*)(bpos + be1));
        cb1 = __builtin_nontemporal_load((const vi4*)(bpos + be1 + 4));
    }

    if (t < NB) { hist0[t] = 0u; hist1[t] = 0u; lcur[t] = 0u; }
    __syncthreads();

    // histogram both chunks
    if (v0) {
        atomicAdd(&hist0[((uint)ab0.x) >> 13], 1u);
        atomicAdd(&hist0[((uint)ab0.y) >> 13], 1u);
        atomicAdd(&hist0[((uint)ab0.z) >> 13], 1u);
        atomicAdd(&hist0[((uint)ab0.w) >> 13], 1u);
        atomicAdd(&hist0[((uint)ab1.x) >> 13], 1u);
        atomicAdd(&hist0[((uint)ab1.y) >> 13], 1u);
        atomicAdd(&hist0[((uint)ab1.z) >> 13], 1u);
        atomicAdd(&hist0[((uint)ab1.w) >> 13], 1u);
    } else {
        for (int j = 0; j < A_EPT; ++j) {
            int e = be0 + j;
            if (e < E) atomicAdd(&hist0[((uint)bpos[e]) >> 13], 1u);
        }
    }
    if (v1) {
        atomicAdd(&hist1[((uint)cb0.x) >> 13], 1u);
        atomicAdd(&hist1[((uint)cb0.y) >> 13], 1u);
        atomicAdd(&hist1[((uint)cb0.z) >> 13], 1u);
        atomicAdd(&hist1[((uint)cb0.w) >> 13], 1u);
        atomicAdd(&hist1[((uint)cb1.x) >> 13], 1u);
        atomicAdd(&hist1[((uint)cb1.y) >> 13], 1u);
        atomicAdd(&hist1[((uint)cb1.z) >> 13], 1u);
        atomicAdd(&hist1[((uint)cb1.w) >> 13], 1u);
    } else {
        for (int j = 0; j < A_EPT; ++j) {
            int e = be1 + j;
            if (e < E) atomicAdd(&hist1[((uint)bpos[e]) >> 13], 1u);
        }
    }
    __syncthreads();

    // wave 0 scans chunk0; waves 8-15 do ONE combined allocation per bucket.
    wave_scan512(hist0, lbase, t);
    if (t >= 512) {
        int b = t - 512;
        gbase[b] = atomicAdd(&gcur[b], hist0[b] + hist1[b]);
    }
    __syncthreads();

    auto emit = [&](int p, int tk, int pi) {
        uint b = ((uint)p) >> 13;
        u64 rec = (u64)(uint)(p & (PPB - 1))
                | ((u64)(uint)tk << 13)
                | ((u64)(uint)pi << 34)
                | ((u64)b << 55);
        uint off = lbase[b] + atomicAdd(&lcur[b], 1u);
        stage[off] = rec;
    };

    // emit chunk0
    if (v0) {
        emit(ab0.x, ak0.x, ap0.x); emit(ab0.y, ak0.y, ap0.y);
        emit(ab0.z, ak0.z, ap0.z); emit(ab0.w, ak0.w, ap0.w);
        emit(ab1.x, ak1.x, ap1.x); emit(ab1.y, ak1.y, ap1.y);
        emit(ab1.z, ak1.z, ap1.z); emit(ab1.w, ak1.w, ap1.w);
    } else {
        for (int j = 0; j < A_EPT; ++j) {
            int e = be0 + j;
            if (e < E) emit(bpos[e], tidx[e], pidx[e]);
        }
    }

    // prefetch chunk1 pidx/tidx now; latency drains under write-out below.
    vi4 cp0, cp1, ck0, ck1;
    if (v1) {
        cp0 = __builtin_nontemporal_load((const vi4*)(pidx + be1));
        cp1 = __builtin_nontemporal_load((const vi4*)(pidx + be1 + 4));
        ck0 = __builtin_nontemporal_load((const vi4*)(tidx + be1));
        ck1 = __builtin_nontemporal_load((const vi4*)(tidx + be1 + 4));
    }
    __syncthreads();

    // write-out chunk0 at gbase (cached stores -> L2 write-combine)
    uint total0 = lbase[NB];
    for (uint i = t; i < total0; i += A_THREADS) {
        u64 rc = stage[i];
        int b = (int)(rc >> 55);
        uint dst = gbase[b] + (i - lbase[b]);
        if (dst < (uint)CAP)
            recs[(size_t)b * CAP + dst] = rc;
    }
    __syncthreads();

    // rescan for chunk1; reset lcur
    if (t < NB) lcur[t] = 0u;
    wave_scan512(hist1, lbase, t);
    __syncthreads();

    // emit chunk1
    if (v1) {
        emit(cb0.x, ck0.x, cp0.x); emit(cb0.y, ck0.y, cp0.y);
        emit(cb0.z, ck0.z, cp0.z); emit(cb0.w, ck0.w, cp0.w);
        emit(cb1.x, ck1.x, cp1.x); emit(cb1.y, ck1.y, cp1.y);
        emit(cb1.z, ck1.z, cp1.z); emit(cb1.w, ck1.w, cp1.w);
    } else {
        for (int j = 0; j < A_EPT; ++j) {
            int e = be1 + j;
            if (e < E) emit(bpos[e], tidx[e], pidx[e]);
        }
    }
    __syncthreads();

    // write-out chunk1 immediately after chunk0's run (256B contiguous)
    uint total1 = lbase[NB];
    for (uint i = t; i < total1; i += A_THREADS) {
        u64 rc = stage[i];
        int b = (int)(rc >> 55);
        uint dst = gbase[b] + hist0[b] + (i - lbase[b]);
        if (dst < (uint)CAP)
            recs[(size_t)b * CAP + dst] = rc;
    }
}

// ------- Phase C: per byte-bucket accumulate + emit token-bucket recs -------
constexpr int C_THREADS = 1024;
constexpr int C_CHUNK   = 8192;
constexpr int C_MAXCH   = (CAP + C_CHUNK - 1) / C_CHUNK;   // 3

__global__ __launch_bounds__(C_THREADS, 8) void phaseC(
    const float* __restrict__ fp,
    const u64* __restrict__ recs, const uint* __restrict__ gcur,
    uint* __restrict__ rec2, uint* __restrict__ gcur2)
{
    __shared__ uint acc[PPB];               // 32 KB
    __shared__ uint stage2[C_CHUNK];        // 32 KB
    __shared__ uint histc[C_MAXCH][NB2];    // 3 KB
    __shared__ uint lcur[NB2], gb[NB2], lbase[NB2 + 1];   // ~3 KB
    int t = threadIdx.x;
    int b = blockIdx.x;
    for (int i = t; i < PPB; i += C_THREADS) acc[i] = 0u;
    for (int i = t; i < C_MAXCH * NB2; i += C_THREADS) (&histc[0][0])[i] = 0u;
    if (t < NB2) lcur[t] = 0u;
    __syncthreads();

    uint n = min(gcur[b], (uint)CAP);
    const u64* r = recs + (size_t)b * CAP;

    // pass 1: strip-mined x4 with COALESCED stride (each NT load = 1KB/wave).
    // 4 independent rec loads -> 8 independent fp gathers -> 16 LDS atomics.
    auto upd = [&](u64 rc, float v, uint ch) {
        int fx = (int)rintf(v * V_SCALE);
        atomicAdd(&acc[(uint)rc & (PPB - 1)], (uint)((1 << 26) + fx));
        atomicAdd(&histc[ch][(uint)(rc >> 26) & 0xFFu], 1u);  // tok>>13
    };
    uint np = n >> 1;                        // uv2 pairs
    const uv2* pr = (const uv2*)r;
    uint i = t;
    for (; i + 3u * C_THREADS < np; i += 4u * C_THREADS) {
        uv2 x0 = __builtin_nontemporal_load(pr + i);
        uv2 x1 = __builtin_nontemporal_load(pr + i + C_THREADS);
        uv2 x2 = __builtin_nontemporal_load(pr + i + 2u * C_THREADS);
        uv2 x3 = __builtin_nontemporal_load(pr + i + 3u * C_THREADS);
        float v0 = fp[(uint)(x0.x >> 34) & 0x1FFFFFu];
        float v1 = fp[(uint)(x0.y >> 34) & 0x1FFFFFu];
        float v2 = fp[(uint)(x1.x >> 34) & 0x1FFFFFu];
        float v3 = fp[(uint)(x1.y >> 34) & 0x1FFFFFu];
        float v4 = fp[(uint)(x2.x >> 34) & 0x1FFFFFu];
        float v5 = fp[(uint)(x2.y >> 34) & 0x1FFFFFu];
        float v6 = fp[(uint)(x3.x >> 34) & 0x1FFFFFu];
        float v7 = fp[(uint)(x3.y >> 34) & 0x1FFFFFu];
        uint c0 = i >> 12;                         // pair>>12 == elem>>13
        uint c1 = (i + C_THREADS) >> 12;
        uint c2 = (i + 2u * C_THREADS) >> 12;
        uint c3 = (i + 3u * C_THREADS) >> 12;
        upd(x0.x, v0, c0); upd(x0.y, v1, c0);
        upd(x1.x, v2, c1); upd(x1.y, v3, c1);
        upd(x2.x, v4, c2); upd(x2.y, v5, c2);
        upd(x3.x, v6, c3); upd(x3.y, v7, c3);
    }
    for (; i < np; i += C_THREADS) {
        uv2 x = __builtin_nontemporal_load(pr + i);
        uint ch = i >> 12;
        float va = fp[(uint)(x.x >> 34) & 0x1FFFFFu];
        float vb = fp[(uint)(x.y >> 34) & 0x1FFFFFu];
        upd(x.x, va, ch); upd(x.y, vb, ch);
    }
    if ((n & 1u) && t == 0) {
        u64 rc = __builtin_nontemporal_load(r + n - 1);
        upd(rc, fp[(uint)(rc >> 34) & 0x1FFFFFu], (n - 1) / C_CHUNK);
    }
    __syncthreads();

    // ONE global-cursor atomic per bucket per block (wave 8), overlapped
    // with wave 0's chunk-0 scan below.
    if (t >= 512 && t < 512 + NB2) {
        int tb = t - 512;
        uint tot = histc[0][tb];
        #pragma unroll
        for (int c = 1; c < C_MAXCH; ++c) tot += histc[c][tb];
        gb[tb] = atomicAdd(&gcur2[tb], tot);
    }

    // pass 2: strip-mined x4 chunked decode + LDS-staged emit + write-out.
    // gb/lcur update folded into write-out (bucket tb owned by wave tb%16
    // in EVERY chunk -> no cross-wave hazard) -> 3 barriers/chunk, not 4.
    auto emit = [&](u64 rc, uint a) {
        uint tok = (uint)(rc >> 13) & 0x1FFFFFu;
        uint c = (a + (1u << 25)) >> 26;        // exact count >= 1
        int s = (int)(a - (c << 26));           // signed sum * 2^21
        float w = (float)s * V_INV / (float)c;
        int wfx = (int)rintf(w * W_SCALE);
        uint tb = tok >> 13;
        uint off = lbase[tb] + atomicAdd(&lcur[tb], 1u);
        stage2[off] = (tok & (TOKB - 1)) | ((uint)wfx << 13);
    };
    uint ch = 0;
    for (uint c0 = 0; c0 < n; c0 += C_CHUNK, ++ch) {
        uint m = min((uint)C_CHUNK, n - c0);
        wave_scan256(histc[ch], lbase, t);
        __syncthreads();

        uint mp = m >> 1;
        const uv2* pc = (const uv2*)(r + c0);
        uint j = t;
        for (; j + 3u * C_THREADS < mp; j += 4u * C_THREADS) {
            uv2 x0 = __builtin_nontemporal_load(pc + j);
            uv2 x1 = __builtin_nontemporal_load(pc + j + C_THREADS);
            uv2 x2 = __builtin_nontemporal_load(pc + j + 2u * C_THREADS);
            uv2 x3 = __builtin_nontemporal_load(pc + j + 3u * C_THREADS);
            uint a0 = acc[(uint)x0.x & (PPB - 1)];
            uint a1 = acc[(uint)x0.y & (PPB - 1)];
            uint a2 = acc[(uint)x1.x & (PPB - 1)];
            uint a3 = acc[(uint)x1.y & (PPB - 1)];
            uint a4 = acc[(uint)x2.x & (PPB - 1)];
            uint a5 = acc[(uint)x2.y & (PPB - 1)];
            uint a6 = acc[(uint)x3.x & (PPB - 1)];
            uint a7 = acc[(uint)x3.y & (PPB - 1)];
            emit(x0.x, a0); emit(x0.y, a1);
            emit(x1.x, a2); emit(x1.y, a3);
            emit(x2.x, a4); emit(x2.y, a5);
            emit(x3.x, a6); emit(x3.y, a7);
        }
        for (; j < mp; j += C_THREADS) {
            uv2 x = __builtin_nontemporal_load(pc + j);
            uint a0 = acc[(uint)x.x & (PPB - 1)];
            uint a1 = acc[(uint)x.y & (PPB - 1)];
            emit(x.x, a0); emit(x.y, a1);
        }
        if ((m & 1u) && t == 0) {
            u64 rc = __builtin_nontemporal_load(r + c0 + m - 1);
            emit(rc, acc[(uint)rc & (PPB - 1)]);
        }
        __syncthreads();
        // write-out: wave w copies buckets w, w+16, ... as contiguous runs
        // (normal cached stores -> rec2 stays L3-resident for phaseD).
        // lane 0 of the owning wave advances gb and resets lcur in-place.
        int w = t >> 6, lane = t & 63;
        for (int tb = w; tb < NB2; tb += 16) {
            uint base = lbase[tb];
            uint len  = lbase[tb + 1] - base;
            uint g    = gb[tb];
            for (uint q = lane; q < len; q += 64) {
                uint dst = g + q;
                if (dst < (uint)CAP2)
                    rec2[(size_t)tb * CAP2 + dst] = stage2[base + q];
            }
            if (lane == 0) { gb[tb] = g + len; lcur[tb] = 0u; }
        }
        __syncthreads();
    }
}

// ---------------- Phase D: per token-bucket reduce + output ----------------
constexpr int D_THREADS = 1024;

__global__ __launch_bounds__(D_THREADS) void phaseD(
    const uint* __restrict__ rec2, const uint* __restrict__ gcur2,
    float* __restrict__ out, int N)
{
    __shared__ int facc[TOKB];   // 32 KB
    int t = threadIdx.x;
    int b = blockIdx.x;
    for (int i = t; i < TOKB; i += D_THREADS) facc[i] = 0;
    __syncthreads();
    uint n = min(gcur2[b], (uint)CAP2);
    const uint* r = rec2 + (size_t)b * CAP2;
    uint n4 = n >> 2;
    uint i = t;
    // 4-deep coalesced load batching: 4 independent uint4 loads, then 16
    // fire-and-forget LDS atomics.
    for (; i + 3u * D_THREADS < n4; i += 4u * D_THREADS) {
        uint4 q0 = ((const uint4*)r)[i];
        uint4 q1 = ((const uint4*)r)[i + D_THREADS];
        uint4 q2 = ((const uint4*)r)[i + 2u * D_THREADS];
        uint4 q3 = ((const uint4*)r)[i + 3u * D_THREADS];
        atomicAdd(&facc[q0.x & (TOKB - 1)], ((int)q0.x) >> 13);
        atomicAdd(&facc[q0.y & (TOKB - 1)], ((int)q0.y) >> 13);
        atomicAdd(&facc[q0.z & (TOKB - 1)], ((int)q0.z) >> 13);
        atomicAdd(&facc[q0.w & (TOKB - 1)], ((int)q0.w) >> 13);
        atomicAdd(&facc[q1.x & (TOKB - 1)], ((int)q1.x) >> 13);
        atomicAdd(&facc[q1.y & (TOKB - 1)], ((int)q1.y) >> 13);
        atomicAdd(&facc[q1.z & (TOKB - 1)], ((int)q1.z) >> 13);
        atomicAdd(&facc[q1.w & (TOKB - 1)], ((int)q1.w) >> 13);
        atomicAdd(&facc[q2.x & (TOKB - 1)], ((int)q2.x) >> 13);
        atomicAdd(&facc[q2.y & (TOKB - 1)], ((int)q2.y) >> 13);
        atomicAdd(&facc[q2.z & (TOKB - 1)], ((int)q2.z) >> 13);
        atomicAdd(&facc[q2.w & (TOKB - 1)], ((int)q2.w) >> 13);
        atomicAdd(&facc[q3.x & (TOKB - 1)], ((int)q3.x) >> 13);
        atomicAdd(&facc[q3.y & (TOKB - 1)], ((int)q3.y) >> 13);
        atomicAdd(&facc[q3.z & (TOKB - 1)], ((int)q3.z) >> 13);
        atomicAdd(&facc[q3.w & (TOKB - 1)], ((int)q3.w) >> 13);
    }
    for (; i < n4; i += D_THREADS) {
        uint4 q = ((const uint4*)r)[i];
        atomicAdd(&facc[q.x & (TOKB - 1)], ((int)q.x) >> 13);
        atomicAdd(&facc[q.y & (TOKB - 1)], ((int)q.y) >> 13);
        atomicAdd(&facc[q.z & (TOKB - 1)], ((int)q.z) >> 13);
        atomicAdd(&facc[q.w & (TOKB - 1)], ((int)q.w) >> 13);
    }
    for (uint k = (n4 << 2) + t; k < n; k += D_THREADS) {
        uint rc = r[k];
        atomicAdd(&facc[rc & (TOKB - 1)], ((int)rc) >> 13);
    }
    __syncthreads();
    int base = b * TOKB;
    for (int i2 = t; i2 < TOKB; i2 += D_THREADS) {
        int idx = base + i2;
        if (idx < N)
            __builtin_nontemporal_store((float)facc[i2] * W_INV, &out[idx]);
    }
}

// ---------------- fallback (R2 path) if workspace too small ----------------
__global__ void fb_scatter(const float* __restrict__ fp,
                           const int* __restrict__ pidx,
                           const int* __restrict__ bpos,
                           u64* __restrict__ bacc, int E) {
    int e = blockIdx.x * blockDim.x + threadIdx.x;
    if (e < E) {
        float v = fp[pidx[e]];
        long long fx = (long long)rintf(v * 4294967296.0f);
        atomicAdd(&bacc[bpos[e]], (1ULL << 39) + (u64)fx);
    }
}

__global__ void fb_tokens(const u64* __restrict__ bacc,
                          const int* __restrict__ bpos,
                          const int* __restrict__ tidx,
                          float* __restrict__ out, int E) {
    int e = blockIdx.x * blockDim.x + threadIdx.x;
    if (e < E) {
        u64 v = bacc[bpos[e]];
        long long cnt = (long long)((v + (1ULL << 38)) >> 39);
        long long s   = (long long)(v - ((u64)cnt << 39));
        atomicAdd(&out[tidx[e]], (float)s * (1.0f / 4294967296.0f) / (float)cnt);
    }
}

extern "C" void kernel_launch(void* const* d_in, const int* in_sizes, int n_in,
                              void* d_out, int out_size, void* d_ws, size_t ws_size,
                              hipStream_t stream) {
    const float* flat_params   = (const float*)d_in[0];
    const int*   occ_param_idx = (const int*)d_in[1];
    const int*   occ_byte_pos  = (const int*)d_in[2];
    const int*   occ_token_idx = (const int*)d_in[3];

    const int E = in_sizes[1];            // 8,388,608
    const int N = out_size;               // 2,097,152

    const size_t REC_BYTES  = (size_t)NB  * CAP  * 8;   // 71.3 MB
    const size_t REC2_BYTES = (size_t)NB2 * CAP2 * 4;   // 35.7 MB
    const size_t NEED = 4096 + REC_BYTES + REC2_BYTES;  // ~107 MB

    if (ws_size >= NEED && N <= NB2 * TOKB) {
        uint* gcur  = (uint*)d_ws;                  // 2 KB (512 u32)
        uint* gcur2 = (uint*)((char*)d_ws + 2048);  // 1 KB (256 u32)
        u64* recs = (u64*)((char*)d_ws + 4096);
        uint* rec2 = (uint*)((char*)d_ws + 4096 + REC_BYTES);

        (void)hipMemsetAsync(d_ws, 0, 4096, stream);   // both cursor arrays

        int nchunks = (E + A_CHUNK - 1) / A_CHUNK;          // 1024
        int gridA = (nchunks + A_CPB - 1) / A_CPB;          // 512
        phaseA<<<gridA, A_THREADS, 0, stream>>>(occ_param_idx, occ_byte_pos,
                                                occ_token_idx, recs, gcur, E);
        phaseC<<<NB, C_THREADS, 0, stream>>>(flat_params, recs, gcur,
                                             rec2, gcur2);
        phaseD<<<NB2, D_THREADS, 0, stream>>>(rec2, gcur2, (float*)d_out, N);
    } else {
        u64* bacc = (u64*)d_ws;
        (void)hipMemsetAsync(bacc, 0, (size_t)4194304 * 8, stream);
        (void)hipMemsetAsync(d_out, 0, (size_t)N * sizeof(float), stream);
        int gridE = (E + 255) / 256;
        fb_scatter<<<gridE, 256, 0, stream>>>(flat_params, occ_param_idx,
                                              occ_byte_pos, bacc, E);
        fb_tokens<<<gridE, 256, 0, stream>>>(bacc, occ_byte_pos,
                                             occ_token_idx, (float*)d_out, E);
    }
}